// Round 1
// baseline (369.780 us; speedup 1.0000x reference)
//
#include <hip/hip_runtime.h>
#include <math.h>

#define NLAB 8
#define BATCH 16
#define ACC_PER_B 56                 // 32 sum_k + 8 cnt_k + 8 cnt_i + 8 agg_sum
#define ACC_FLOATS (BATCH * ACC_PER_B)
#define LAB_OFFSET 4096              // label byte-cache starts here in d_ws

__device__ __forceinline__ float wave_reduce(float v) {
#pragma unroll
  for (int off = 32; off > 0; off >>= 1) v += __shfl_xor(v, off, 64);
  return v;
}

// Pass 1: per-batch segment sums (kernel-region emb sums + counts, and
// full-region pixel counts). Register-accumulated, wave-reduced, then one
// global atomicAdd per wave per slot. Optionally caches per-pixel label byte.
__global__ __launch_bounds__(256) void k_accum(
    const float4* __restrict__ emb, const int* __restrict__ inst,
    const float* __restrict__ ker, const float* __restrict__ tmk,
    float* __restrict__ acc, unsigned char* __restrict__ labc,
    int P, int use_cache)
{
  const int b = blockIdx.y;
  const size_t base = (size_t)b * P;
  const float4* e  = emb + base;
  const int*    ip = inst + base;
  const float*  kp = ker + base;
  const float*  tp = tmk + base;

  float s[NLAB][4];
  float ck[NLAB], ci[NLAB];
#pragma unroll
  for (int l = 0; l < NLAB; ++l) {
    ck[l] = 0.f; ci[l] = 0.f;
    s[l][0] = 0.f; s[l][1] = 0.f; s[l][2] = 0.f; s[l][3] = 0.f;
  }

  const int stride = blockDim.x * gridDim.x;
  for (int p = blockIdx.x * blockDim.x + threadIdx.x; p < P; p += stride) {
    int   iv = ip[p];
    float tv = tp[p];
    float kv = kp[p];
    float4 ev = e[p];
    int lab = (tv > 0.5f) ? (iv & (NLAB - 1)) : 0;
    float krf = (kv > 0.5f) ? 1.f : 0.f;
    if (use_cache) labc[base + p] = (unsigned char)lab;
#pragma unroll
    for (int l = 0; l < NLAB; ++l) {
      float mi = (lab == l) ? 1.f : 0.f;
      float mk = mi * krf;
      ci[l] += mi;
      ck[l] += mk;
      s[l][0] = fmaf(mk, ev.x, s[l][0]);
      s[l][1] = fmaf(mk, ev.y, s[l][1]);
      s[l][2] = fmaf(mk, ev.z, s[l][2]);
      s[l][3] = fmaf(mk, ev.w, s[l][3]);
    }
  }

  const int lane = threadIdx.x & 63;
  float* accB = acc + b * ACC_PER_B;
#pragma unroll
  for (int l = 0; l < NLAB; ++l) {
#pragma unroll
    for (int c = 0; c < 4; ++c) {
      float v = wave_reduce(s[l][c]);
      if (lane == 0) atomicAdd(&accB[l * 4 + c], v);
    }
    float vk = wave_reduce(ck[l]);
    if (lane == 0) atomicAdd(&accB[32 + l], vk);
    float vi = wave_reduce(ci[l]);
    if (lane == 0) atomicAdd(&accB[40 + l], vi);
  }
}

// Pass 2: aggregation term per pixel against mu (computed from pass-1 sums),
// segment-summed into acc[48+l]. Only labels 2..7 contribute to the final
// l_agg = mean(agg[2:]), so labels 0,1 are skipped.
__global__ __launch_bounds__(256) void k_agg(
    const float4* __restrict__ emb, const int* __restrict__ inst,
    const float* __restrict__ tmk, const unsigned char* __restrict__ labc,
    float* __restrict__ acc, int P, int use_cache)
{
  const int b = blockIdx.y;
  const size_t base = (size_t)b * P;
  __shared__ float mu[NLAB][4];
  const float* accB = acc + b * ACC_PER_B;
  if (threadIdx.x < NLAB * 4) {
    int l = threadIdx.x >> 2, c = threadIdx.x & 3;
    float m = accB[l * 4 + c] / fmaxf(accB[32 + l], 1.f);
    mu[l][c] = (l == 0) ? 0.f : m;
  }
  __syncthreads();

  const float4* e  = emb + base;
  const int*    ip = inst + base;
  const float*  tp = tmk + base;
  const unsigned char* lp = labc + base;

  float aggl[6];
#pragma unroll
  for (int l = 0; l < 6; ++l) aggl[l] = 0.f;

  const int stride = blockDim.x * gridDim.x;
  for (int p = blockIdx.x * blockDim.x + threadIdx.x; p < P; p += stride) {
    int lab;
    if (use_cache) {
      lab = lp[p];
    } else {
      int iv = ip[p]; float tv = tp[p];
      lab = (tv > 0.5f) ? (iv & (NLAB - 1)) : 0;
    }
    if (lab >= 2) {
      float4 ev = e[p];
      float dx = ev.x - mu[lab][0];
      float dy = ev.y - mu[lab][1];
      float dz = ev.z - mu[lab][2];
      float dw = ev.w - mu[lab][3];
      float sq = dx * dx + dy * dy + dz * dz + dw * dw;
      float d = sqrtf(sq);                       // exact at 0, matches _safe_norm fwd
      float t = fmaxf(d - 0.5f, 0.f);            // DELTA_V
      float term = logf(fmaf(t, t, 1.f));
#pragma unroll
      for (int l = 0; l < 6; ++l) aggl[l] += (lab == l + 2) ? term : 0.f;
    }
  }

  const int lane = threadIdx.x & 63;
#pragma unroll
  for (int l = 0; l < 6; ++l) {
    float v = wave_reduce(aggl[l]);
    if (lane == 0) atomicAdd(&acc[b * ACC_PER_B + 48 + 2 + l], v);
  }
}

// Finalize: one wave; lane b handles batch b, then wave-reduce the batch mean.
__global__ void k_final(const float* __restrict__ acc, float* __restrict__ out, int nb) {
  const int lane = threadIdx.x;
  float loss = 0.f;
  if (lane < nb) {
    const float* a = acc + lane * ACC_PER_B;
    float mu[NLAB][4];
#pragma unroll
    for (int l = 0; l < NLAB; ++l) {
      float cnt = fmaxf(a[32 + l], 1.f);
#pragma unroll
      for (int c = 0; c < 4; ++c)
        mu[l][c] = (l == 0) ? 0.f : a[l * 4 + c] / cnt;
    }
    // l_agg = mean over labels 2..7 of agg_sum / max(cnt_i,1)
    float l_agg = 0.f;
#pragma unroll
    for (int l = 2; l < NLAB; ++l)
      l_agg += a[48 + l] / fmaxf(a[40 + l], 1.f);
    l_agg *= (1.f / 6.f);
    // l_dis over ordered pairs i!=j, i,j in 1..7 (42 pairs)
    float ssum = 0.f;
    for (int i = 1; i < NLAB; ++i)
      for (int j = 1; j < NLAB; ++j) {
        if (i == j) continue;
        float dx = mu[i][0] - mu[j][0], dy = mu[i][1] - mu[j][1];
        float dz = mu[i][2] - mu[j][2], dw = mu[i][3] - mu[j][3];
        float dd = sqrtf(dx * dx + dy * dy + dz * dz + dw * dw);
        float t = fmaxf(3.0f - dd, 0.f);         // 2*DELTA_D
        ssum += logf(fmaf(t, t, 1.f));
      }
    float l_dis = ssum / 42.f;
    // l_reg = mean over all 8 labels of log(||mu||+1) * 0.001
    float rsum = 0.f;
#pragma unroll
    for (int l = 0; l < NLAB; ++l) {
      float n = sqrtf(mu[l][0] * mu[l][0] + mu[l][1] * mu[l][1] +
                      mu[l][2] * mu[l][2] + mu[l][3] * mu[l][3]);
      rsum += logf(n + 1.f);
    }
    float l_reg = rsum * (0.001f / NLAB);
    loss = l_agg + l_dis + l_reg;
  }
  loss = wave_reduce(loss);
  if (lane == 0) out[0] = loss / (float)nb;      // LOSS_WEIGHT = 1
}

extern "C" void kernel_launch(void* const* d_in, const int* in_sizes, int n_in,
                              void* d_out, int out_size, void* d_ws, size_t ws_size,
                              hipStream_t stream) {
  const float4* emb = (const float4*)d_in[0];
  const int*    inst = (const int*)d_in[1];
  const float*  ker  = (const float*)d_in[2];
  const float*  tmk  = (const float*)d_in[3];
  float* out = (float*)d_out;

  const int total = in_sizes[1];       // B*H*W
  const int P = total / BATCH;

  float* acc = (float*)d_ws;
  unsigned char* labc = (unsigned char*)d_ws + LAB_OFFSET;
  const size_t need = (size_t)LAB_OFFSET + (size_t)total;
  const int use_cache = (ws_size >= need) ? 1 : 0;

  // d_ws is re-poisoned to 0xAA before every launch — zero the accumulators.
  hipMemsetAsync(d_ws, 0, ACC_FLOATS * sizeof(float), stream);

  dim3 grid(64, BATCH);                // 1024 blocks, 4/CU; 25 px/thread
  k_accum<<<grid, 256, 0, stream>>>(emb, inst, ker, tmk, acc, labc, P, use_cache);
  k_agg  <<<grid, 256, 0, stream>>>(emb, inst, tmk, labc, acc, P, use_cache);
  k_final<<<1, 64, 0, stream>>>(acc, out, BATCH);
}

// Round 2
// 249.214 us; speedup vs baseline: 1.4838x; 1.4838x over previous
//
#include <hip/hip_runtime.h>
#include <math.h>

#define NLAB 8
#define BATCH 16
// acc layout per batch (floats):
//   [0..27]  emb sums, labels 1..7 x 4 ch
//   [28..34] cnt_k, labels 1..7
//   [35..40] cnt_i, labels 2..7
//   [41..46] agg sums, labels 2..7
#define S_OFF  0
#define CK_OFF 28
#define CI_OFF 35
#define AG_OFF 41
#define ACC_PER_B 48
#define ACC_FLOATS (BATCH * ACC_PER_B)
#define LAB_OFFSET 4096              // label byte-cache starts here in d_ws

__device__ __forceinline__ float wave_reduce(float v) {
#pragma unroll
  for (int off = 32; off > 0; off >>= 1) v += __shfl_xor(v, off, 64);
  return v;
}

// ---------------------------------------------------------------------------
// Pass 1: per-batch segment sums. 4 px/thread/iter via int4/float4 loads.
// 41 register accumulators (labels 1..7 only; label-0 sums are never used:
// mu[0] is forced to 0 and l_agg only uses labels 2..7).
// __launch_bounds__(256,4): 128-VGPR budget so the accumulators DON'T spill
// (R1's 36-VGPR build spilled 48 accumulators to scratch -> 540 GB/s).
// ---------------------------------------------------------------------------
__global__ __launch_bounds__(256, 4) void k_accum(
    const float4* __restrict__ emb, const int* __restrict__ inst,
    const float* __restrict__ ker, const float* __restrict__ tmk,
    float* __restrict__ acc, unsigned int* __restrict__ labc,
    int P, int use_cache)
{
  const int b = blockIdx.y;
  const size_t base = (size_t)b * P;
  const float4* e   = emb + base;
  const int4*   ip4 = (const int4*)(inst + base);
  const float4* kp4 = (const float4*)(ker + base);
  const float4* tp4 = (const float4*)(tmk + base);
  unsigned int* lb  = labc + (base >> 2);

  float s[7][4], ck[7], ci[6];
#pragma unroll
  for (int l = 0; l < 7; ++l) {
    ck[l] = 0.f;
    s[l][0] = 0.f; s[l][1] = 0.f; s[l][2] = 0.f; s[l][3] = 0.f;
  }
#pragma unroll
  for (int l = 0; l < 6; ++l) ci[l] = 0.f;

  const int nq = P >> 2;               // quads of pixels
  const int stride = blockDim.x * gridDim.x;

  for (int q = blockIdx.x * blockDim.x + threadIdx.x; q < nq; q += stride) {
    int4   iv = ip4[q];
    float4 kv = kp4[q];
    float4 tv = tp4[q];
    float4 e0 = e[4 * q + 0];
    float4 e1 = e[4 * q + 1];
    float4 e2 = e[4 * q + 2];
    float4 e3 = e[4 * q + 3];

    int lab0 = (tv.x > 0.5f) ? (iv.x & 7) : 0;
    int lab1 = (tv.y > 0.5f) ? (iv.y & 7) : 0;
    int lab2 = (tv.z > 0.5f) ? (iv.z & 7) : 0;
    int lab3 = (tv.w > 0.5f) ? (iv.w & 7) : 0;
    float k0 = (kv.x > 0.5f) ? 1.f : 0.f;
    float k1 = (kv.y > 0.5f) ? 1.f : 0.f;
    float k2 = (kv.z > 0.5f) ? 1.f : 0.f;
    float k3 = (kv.w > 0.5f) ? 1.f : 0.f;

    if (use_cache)
      lb[q] = (unsigned)lab0 | ((unsigned)lab1 << 8) |
              ((unsigned)lab2 << 16) | ((unsigned)lab3 << 24);

#pragma unroll
    for (int l = 1; l < NLAB; ++l) {
      float m0 = (lab0 == l) ? 1.f : 0.f;
      float m1 = (lab1 == l) ? 1.f : 0.f;
      float m2 = (lab2 == l) ? 1.f : 0.f;
      float m3 = (lab3 == l) ? 1.f : 0.f;
      float mk0 = m0 * k0, mk1 = m1 * k1, mk2 = m2 * k2, mk3 = m3 * k3;
      ck[l - 1] += (mk0 + mk1) + (mk2 + mk3);
      s[l - 1][0] = fmaf(mk0, e0.x, fmaf(mk1, e1.x, fmaf(mk2, e2.x, fmaf(mk3, e3.x, s[l - 1][0]))));
      s[l - 1][1] = fmaf(mk0, e0.y, fmaf(mk1, e1.y, fmaf(mk2, e2.y, fmaf(mk3, e3.y, s[l - 1][1]))));
      s[l - 1][2] = fmaf(mk0, e0.z, fmaf(mk1, e1.z, fmaf(mk2, e2.z, fmaf(mk3, e3.z, s[l - 1][2]))));
      s[l - 1][3] = fmaf(mk0, e0.w, fmaf(mk1, e1.w, fmaf(mk2, e2.w, fmaf(mk3, e3.w, s[l - 1][3]))));
      if (l >= 2) ci[l - 2] += (m0 + m1) + (m2 + m3);
    }
  }

  // handle pixel tail if P not divisible by 4 (robustness; P=409600 here)
  const int tail = P - (nq << 2);
  const int gtid = blockIdx.x * blockDim.x + threadIdx.x;
  if (gtid < tail) {
    int p = (nq << 2) + gtid;
    int lab = (tmk[base + p] > 0.5f) ? (inst[base + p] & 7) : 0;
    float kr = (ker[base + p] > 0.5f) ? 1.f : 0.f;
    float4 ev = e[p];
    if (use_cache)
      atomicAnd(&lb[p >> 2], ~(255u << (8 * (p & 3)))),
      atomicOr(&lb[p >> 2], (unsigned)lab << (8 * (p & 3)));
#pragma unroll
    for (int l = 1; l < NLAB; ++l) {
      float m = (lab == l) ? 1.f : 0.f;
      float mk = m * kr;
      ck[l - 1] += mk;
      s[l - 1][0] = fmaf(mk, ev.x, s[l - 1][0]);
      s[l - 1][1] = fmaf(mk, ev.y, s[l - 1][1]);
      s[l - 1][2] = fmaf(mk, ev.z, s[l - 1][2]);
      s[l - 1][3] = fmaf(mk, ev.w, s[l - 1][3]);
      if (l >= 2) ci[l - 2] += m;
    }
  }

  // block-level reduction: wave_reduce -> LDS -> one atomic per block per slot
  __shared__ float red[4][48];
  const int wid = threadIdx.x >> 6, lane = threadIdx.x & 63;
#pragma unroll
  for (int l = 0; l < 7; ++l) {
#pragma unroll
    for (int c = 0; c < 4; ++c) {
      float v = wave_reduce(s[l][c]);
      if (lane == 0) red[wid][S_OFF + l * 4 + c] = v;
    }
    float vk = wave_reduce(ck[l]);
    if (lane == 0) red[wid][CK_OFF + l] = vk;
  }
#pragma unroll
  for (int l = 0; l < 6; ++l) {
    float vi = wave_reduce(ci[l]);
    if (lane == 0) red[wid][CI_OFF + l] = vi;
  }
  __syncthreads();
  if (threadIdx.x < AG_OFF) {
    float v = red[0][threadIdx.x] + red[1][threadIdx.x] +
              red[2][threadIdx.x] + red[3][threadIdx.x];
    atomicAdd(acc + b * ACC_PER_B + threadIdx.x, v);
  }
}

// ---------------------------------------------------------------------------
// Pass 2: aggregation term vs mu, labels 2..7 only. emb should be L3-resident
// after pass 1 (105 MB < 256 MB L3).
// ---------------------------------------------------------------------------
__global__ __launch_bounds__(256, 4) void k_agg(
    const float4* __restrict__ emb, const int* __restrict__ inst,
    const float* __restrict__ tmk, const unsigned int* __restrict__ labc,
    float* __restrict__ acc, int P, int use_cache)
{
  const int b = blockIdx.y;
  const size_t base = (size_t)b * P;
  __shared__ float4 smu[NLAB];
  const float* accB = acc + b * ACC_PER_B;
  if (threadIdx.x < NLAB) {
    int l = threadIdx.x;
    float4 m;
    if (l == 0) {
      m = make_float4(0.f, 0.f, 0.f, 0.f);
    } else {
      float inv = 1.f / fmaxf(accB[CK_OFF + l - 1], 1.f);
      m = make_float4(accB[S_OFF + (l - 1) * 4 + 0] * inv,
                      accB[S_OFF + (l - 1) * 4 + 1] * inv,
                      accB[S_OFF + (l - 1) * 4 + 2] * inv,
                      accB[S_OFF + (l - 1) * 4 + 3] * inv);
    }
    smu[l] = m;
  }
  __syncthreads();

  const float4* e = emb + base;
  const unsigned int* lb = labc + (base >> 2);
  const int4*   ip4 = (const int4*)(inst + base);
  const float4* tp4 = (const float4*)(tmk + base);

  float aggl[6];
#pragma unroll
  for (int l = 0; l < 6; ++l) aggl[l] = 0.f;

  const int nq = P >> 2;
  const int stride = blockDim.x * gridDim.x;

  for (int q = blockIdx.x * blockDim.x + threadIdx.x; q < nq; q += stride) {
    int lab0, lab1, lab2, lab3;
    if (use_cache) {
      unsigned lu = lb[q];
      lab0 = lu & 255; lab1 = (lu >> 8) & 255;
      lab2 = (lu >> 16) & 255; lab3 = (lu >> 24) & 255;
    } else {
      int4 iv = ip4[q]; float4 tv = tp4[q];
      lab0 = (tv.x > 0.5f) ? (iv.x & 7) : 0;
      lab1 = (tv.y > 0.5f) ? (iv.y & 7) : 0;
      lab2 = (tv.z > 0.5f) ? (iv.z & 7) : 0;
      lab3 = (tv.w > 0.5f) ? (iv.w & 7) : 0;
    }
    float4 e0 = e[4 * q + 0];
    float4 e1 = e[4 * q + 1];
    float4 e2 = e[4 * q + 2];
    float4 e3 = e[4 * q + 3];

#pragma unroll
    for (int i = 0; i < 4; ++i) {
      int lab = (i == 0) ? lab0 : (i == 1) ? lab1 : (i == 2) ? lab2 : lab3;
      float4 ev = (i == 0) ? e0 : (i == 1) ? e1 : (i == 2) ? e2 : e3;
      float4 mv = smu[lab];
      float dx = ev.x - mv.x, dy = ev.y - mv.y;
      float dz = ev.z - mv.z, dw = ev.w - mv.w;
      float sq = dx * dx + dy * dy + dz * dz + dw * dw;
      float d = sqrtf(sq);
      float t = fmaxf(d - 0.5f, 0.f);                  // DELTA_V
      float term = (lab >= 2) ? logf(fmaf(t, t, 1.f)) : 0.f;
#pragma unroll
      for (int l = 0; l < 6; ++l) aggl[l] += (lab == l + 2) ? term : 0.f;
    }
  }

  const int tail = P - (nq << 2);
  const int gtid = blockIdx.x * blockDim.x + threadIdx.x;
  if (gtid < tail) {
    int p = (nq << 2) + gtid;
    int lab = (tmk[base + p] > 0.5f) ? (inst[base + p] & 7) : 0;
    float4 ev = e[p];
    float4 mv = smu[lab];
    float dx = ev.x - mv.x, dy = ev.y - mv.y;
    float dz = ev.z - mv.z, dw = ev.w - mv.w;
    float d = sqrtf(dx * dx + dy * dy + dz * dz + dw * dw);
    float t = fmaxf(d - 0.5f, 0.f);
    float term = (lab >= 2) ? logf(fmaf(t, t, 1.f)) : 0.f;
#pragma unroll
    for (int l = 0; l < 6; ++l) aggl[l] += (lab == l + 2) ? term : 0.f;
  }

  __shared__ float red[4][8];
  const int wid = threadIdx.x >> 6, lane = threadIdx.x & 63;
#pragma unroll
  for (int l = 0; l < 6; ++l) {
    float v = wave_reduce(aggl[l]);
    if (lane == 0) red[wid][l] = v;
  }
  __syncthreads();
  if (threadIdx.x < 6) {
    float v = red[0][threadIdx.x] + red[1][threadIdx.x] +
              red[2][threadIdx.x] + red[3][threadIdx.x];
    atomicAdd(acc + b * ACC_PER_B + AG_OFF + threadIdx.x, v);
  }
}

// ---------------------------------------------------------------------------
// Finalize: one wave; lane b handles batch b, then wave-reduce the batch mean.
// ---------------------------------------------------------------------------
__global__ void k_final(const float* __restrict__ acc, float* __restrict__ out, int nb) {
  const int lane = threadIdx.x;
  float loss = 0.f;
  if (lane < nb) {
    const float* a = acc + lane * ACC_PER_B;
    float mu[NLAB][4];
#pragma unroll
    for (int c = 0; c < 4; ++c) mu[0][c] = 0.f;
#pragma unroll
    for (int l = 1; l < NLAB; ++l) {
      float inv = 1.f / fmaxf(a[CK_OFF + l - 1], 1.f);
#pragma unroll
      for (int c = 0; c < 4; ++c) mu[l][c] = a[S_OFF + (l - 1) * 4 + c] * inv;
    }
    // l_agg = mean over labels 2..7 of agg_sum / max(cnt_i,1)
    float l_agg = 0.f;
#pragma unroll
    for (int l = 2; l < NLAB; ++l)
      l_agg += a[AG_OFF + l - 2] / fmaxf(a[CI_OFF + l - 2], 1.f);
    l_agg *= (1.f / 6.f);
    // l_dis over ordered pairs i!=j, i,j in 1..7 (42 pairs)
    float ssum = 0.f;
    for (int i = 1; i < NLAB; ++i)
      for (int j = 1; j < NLAB; ++j) {
        if (i == j) continue;
        float dx = mu[i][0] - mu[j][0], dy = mu[i][1] - mu[j][1];
        float dz = mu[i][2] - mu[j][2], dw = mu[i][3] - mu[j][3];
        float dd = sqrtf(dx * dx + dy * dy + dz * dz + dw * dw);
        float t = fmaxf(3.0f - dd, 0.f);         // 2*DELTA_D
        ssum += logf(fmaf(t, t, 1.f));
      }
    float l_dis = ssum / 42.f;
    // l_reg: mu[0]=0 contributes log(1)=0; mean over all 8 labels
    float rsum = 0.f;
#pragma unroll
    for (int l = 1; l < NLAB; ++l) {
      float n = sqrtf(mu[l][0] * mu[l][0] + mu[l][1] * mu[l][1] +
                      mu[l][2] * mu[l][2] + mu[l][3] * mu[l][3]);
      rsum += logf(n + 1.f);
    }
    float l_reg = rsum * (0.001f / NLAB);
    loss = l_agg + l_dis + l_reg;
  }
  loss = wave_reduce(loss);
  if (lane == 0) out[0] = loss / (float)nb;      // LOSS_WEIGHT = 1
}

extern "C" void kernel_launch(void* const* d_in, const int* in_sizes, int n_in,
                              void* d_out, int out_size, void* d_ws, size_t ws_size,
                              hipStream_t stream) {
  const float4* emb = (const float4*)d_in[0];
  const int*    inst = (const int*)d_in[1];
  const float*  ker  = (const float*)d_in[2];
  const float*  tmk  = (const float*)d_in[3];
  float* out = (float*)d_out;

  const int total = in_sizes[1];       // B*H*W
  const int P = total / BATCH;

  float* acc = (float*)d_ws;
  unsigned int* labc = (unsigned int*)((char*)d_ws + LAB_OFFSET);
  const size_t need = (size_t)LAB_OFFSET + (size_t)total;
  const int use_cache = (ws_size >= need && (P & 3) == 0) ? 1 : 0;

  // d_ws is re-poisoned to 0xAA before every launch — zero the accumulators.
  hipMemsetAsync(d_ws, 0, ACC_FLOATS * sizeof(float), stream);

  dim3 grid(128, BATCH);               // 2048 blocks, 8/CU oversubscribed
  k_accum<<<grid, 256, 0, stream>>>(emb, inst, ker, tmk, acc, labc, P, use_cache);
  k_agg  <<<grid, 256, 0, stream>>>(emb, inst, tmk, labc, acc, P, use_cache);
  k_final<<<1, 64, 0, stream>>>(acc, out, BATCH);
}